// Round 1
// baseline (5108.258 us; speedup 1.0000x reference)
//
#include <hip/hip_runtime.h>
#include <cstdint>

#define BB 256
#define TT 4096
#define FDIM 16
#define HH 128
#define OO 2

// ---------------------------------------------------------------------------
// Kernel A: delta encoding -> 32-bit spike masks per (b, t).
// bits 0..15 = ON spikes (feature f), bits 16..31 = OFF spikes.
// mask[b][0] = 0 (reference emits a zero row at t=0).
// Exact: only compares and exact assignments -> bitwise matches reference.
// One wave per block handles 4 batches (lane = sub*16 + f).
// ---------------------------------------------------------------------------
__global__ __launch_bounds__(64) void snn_encode(const float* __restrict__ x,
                                                 uint32_t* __restrict__ masks) {
  const int lane = threadIdx.x;
  const int sub = lane >> 4;
  const int f = lane & 15;
  const int b = blockIdx.x * 4 + sub;
  const float* xb = x + (size_t)b * (TT * FDIM) + f;
  float ref = xb[0];
  if (f == 0) masks[(size_t)b * TT] = 0u;
  for (int t0 = 1; t0 < TT; t0 += 4) {
    float c[4];
#pragma unroll
    for (int i = 0; i < 4; ++i) {
      int t = t0 + i;
      c[i] = (t < TT) ? xb[(size_t)t * FDIM] : 0.f;
    }
#pragma unroll
    for (int i = 0; i < 4; ++i) {
      int t = t0 + i;
      if (t < TT) {
        float diff = c[i] - ref;
        bool on = diff >= 0.5f;
        bool off = diff <= -0.5f;
        unsigned long long bon = __ballot(on);
        unsigned long long boff = __ballot(off);
        if (on || off) ref = c[i];  // exact ref update (mask is 0/1)
        if (f == 0) {
          uint32_t m = (uint32_t)((bon >> (sub * 16)) & 0xFFFFull) |
                       ((uint32_t)((boff >> (sub * 16)) & 0xFFFFull) << 16);
          masks[(size_t)b * TT + t] = m;
        }
      }
    }
  }
}

// 64-lane sum via DPP (VALU pipe, no LDS round trips). Result broadcast from
// lane 63. Tree order differs from reference j-order, but L3 feeds only the
// continuous m3 output (|m3| << threshold 1.0, reset3 handled anyway), so
// ~1e-7 reorder wobble is harmless there.
__device__ __forceinline__ float wave_red_add(float v) {
#define DPP_ADD(c)                                                             \
  v += __int_as_float(                                                         \
      __builtin_amdgcn_update_dpp(0, __float_as_int(v), c, 0xF, 0xF, true))
  DPP_ADD(0x111);  // row_shr:1
  DPP_ADD(0x112);  // row_shr:2
  DPP_ADD(0x114);  // row_shr:4
  DPP_ADD(0x118);  // row_shr:8
  DPP_ADD(0x142);  // row_bcast:15
  DPP_ADD(0x143);  // row_bcast:31
#undef DPP_ADD
  return __int_as_float(__builtin_amdgcn_readlane(__float_as_int(v), 63));
}

// ---------------------------------------------------------------------------
// Kernel C: serial SNN core. One wave per batch element (256 blocks = 256 CUs).
// Lane l owns neurons h=l and h=64+l  =>  __ballot bit l maps to h ascending,
// so sparse set-bit iteration reproduces the reference's ascending-k matmul
// accumulation order bitwise (adding only the spike==1 columns is exact).
// W1^T (16KB) and W2^T (64KB) live in LDS; column reads are 2-way bank
// aliases (free on CDNA4).
// ---------------------------------------------------------------------------
__global__ __launch_bounds__(64) void snn_core(
    const uint32_t* __restrict__ masks, const float* __restrict__ W1,
    const float* __restrict__ b1, const float* __restrict__ W2,
    const float* __restrict__ b2, const float* __restrict__ W3,
    const float* __restrict__ b3, float* __restrict__ out) {
  __shared__ float W1c[32 * HH];    // W1c[j*128 + h] = W1[h][j]
  __shared__ float W2c[HH * HH];    // W2c[j*128 + h] = W2[h][j]
  const int lane = threadIdx.x;
  const int b = blockIdx.x;

  // Coalesced global reads; transposed LDS writes (one-time bank conflicts OK).
  for (int i = lane; i < 32 * HH; i += 64) {
    int h = i >> 5, j = i & 31;
    W1c[j * HH + h] = W1[i];
  }
  for (int i = lane; i < HH * HH; i += 64) {
    int h = i >> 7, j = i & 127;
    W2c[j * HH + h] = W2[i];
  }
  const float b1a = b1[lane], b1b = b1[64 + lane];
  const float b2a = b2[lane], b2b = b2[64 + lane];
  const float w30a = W3[lane], w30b = W3[64 + lane];
  const float w31a = W3[HH + lane], w31b = W3[HH + 64 + lane];
  const float b30 = b3[0], b31 = b3[1];
  __syncthreads();

  float m1a = 0.f, m1b = 0.f;
  float m2a = 0.f, m2b = 0.f;
  float m3x = 0.f, m3y = 0.f;
  const uint32_t* mp = masks + (size_t)b * TT;
  uint32_t mcur = mp[0];

  for (int t = 0; t < TT; ++t) {
    // Prefetch next step's mask (uniform -> scalar load, hidden under body).
    uint32_t mnext = mp[(t + 1) & (TT - 1)];

    // ---- Layer 1 current: sum of active W1 columns, ascending j, then bias.
    float a0 = 0.f, a1 = 0.f;
    uint32_t mm = mcur;
    while (mm) {
      int j = __builtin_ctz(mm);
      mm &= mm - 1;
      a0 += W1c[j * HH + lane];
      a1 += W1c[j * HH + 64 + lane];
    }
    a0 += b1a;
    a1 += b1b;

    // ---- LIF1: reset from PRE-update mem; mul then add (matches np rounding).
    float n0 = __fadd_rn(__fmul_rn(0.9f, m1a), a0);
    float n1 = __fadd_rn(__fmul_rn(0.9f, m1b), a1);
    m1a = (m1a > 1.f) ? (n0 - 1.f) : n0;
    m1b = (m1b > 1.f) ? (n1 - 1.f) : n1;
    unsigned long long s0 = __ballot(m1a > 1.f);  // h = 0..63
    unsigned long long s1 = __ballot(m1b > 1.f);  // h = 64..127

    // ---- Layer 2 current: sparse column sum over spk1, ascending h.
    float c0 = 0.f, c1 = 0.f;
    unsigned long long bb2 = s0;
    while (bb2) {
      int j = __builtin_ctzll(bb2);
      bb2 &= bb2 - 1;
      c0 += W2c[j * HH + lane];
      c1 += W2c[j * HH + 64 + lane];
    }
    bb2 = s1;
    while (bb2) {
      int j = __builtin_ctzll(bb2);
      bb2 &= bb2 - 1;
      c0 += W2c[(64 + j) * HH + lane];
      c1 += W2c[(64 + j) * HH + 64 + lane];
    }
    c0 += b2a;
    c1 += b2b;

    // ---- LIF2
    float u0 = __fadd_rn(__fmul_rn(0.9f, m2a), c0);
    float u1 = __fadd_rn(__fmul_rn(0.9f, m2b), c1);
    m2a = (m2a > 1.f) ? (u0 - 1.f) : u0;
    m2b = (m2b > 1.f) ? (u1 - 1.f) : u1;
    bool q0 = m2a > 1.f;
    bool q1 = m2b > 1.f;

    // ---- Layer 3 (O=2): per-lane partials, DPP wave reduction, bias after.
    float p0 = (q0 ? w30a : 0.f) + (q1 ? w30b : 0.f);
    float p1 = (q0 ? w31a : 0.f) + (q1 ? w31b : 0.f);
    float cur3x = wave_red_add(p0) + b30;
    float cur3y = wave_red_add(p1) + b31;

    // ---- LIF3 (spike unused; reset kept for exactness)
    float v0 = __fadd_rn(__fmul_rn(0.9f, m3x), cur3x);
    float v1 = __fadd_rn(__fmul_rn(0.9f, m3y), cur3y);
    m3x = (m3x > 1.f) ? (v0 - 1.f) : v0;
    m3y = (m3y > 1.f) ? (v1 - 1.f) : v1;

    if (lane == 0) {
      size_t o = ((size_t)t * BB + b) * 2;
      out[o] = m3x;
      out[o + 1] = m3y;
    }
    mcur = mnext;
  }
}

extern "C" void kernel_launch(void* const* d_in, const int* in_sizes, int n_in,
                              void* d_out, int out_size, void* d_ws,
                              size_t ws_size, hipStream_t stream) {
  const float* x = (const float*)d_in[0];
  const float* W1 = (const float*)d_in[1];
  const float* b1 = (const float*)d_in[2];
  const float* W2 = (const float*)d_in[3];
  const float* b2 = (const float*)d_in[4];
  const float* W3 = (const float*)d_in[5];
  const float* b3 = (const float*)d_in[6];
  float* out = (float*)d_out;
  uint32_t* masks = (uint32_t*)d_ws;  // needs B*T*4 = 4 MiB of workspace

  snn_encode<<<BB / 4, 64, 0, stream>>>(x, masks);
  snn_core<<<BB, 64, 0, stream>>>(masks, W1, b1, W2, b2, W3, b3, out);
}